// Round 2
// baseline (196.178 us; speedup 1.0000x reference)
//
#include <hip/hip_runtime.h>
#include <hip/hip_bf16.h>
#include <stdint.h>

typedef __bf16 bf16_t;
typedef __bf16 bf16x8 __attribute__((ext_vector_type(8)));
typedef float f32x4 __attribute__((ext_vector_type(4)));

#define DEVI __device__ __forceinline__

constexpr int BB = 2;       // batch
constexpr int SS = 4096;    // seq
constexpr int EE = 1024;    // embed
constexpr int HH = 16;      // heads
constexpr int DD = 64;      // head dim
constexpr int MM = BB * SS; // 8192 token rows

// async global->LDS, 16B per lane; LDS dest must be wave-uniform base (HW adds lane*16)
DEVI void gload16(const void* g, void* l) {
  __builtin_amdgcn_global_load_lds(
      (const __attribute__((address_space(1))) void*)g,
      (__attribute__((address_space(3))) void*)l, 16, 0, 0);
}

// ---------------- f32 -> bf16 convert (vectorized 8/thread) ----------------
__global__ void cvt_kernel(const float* __restrict__ in, bf16_t* __restrict__ out, int n8) {
  int i = blockIdx.x * 256 + threadIdx.x;
  if (i >= n8) return;
  const float* p = in + (size_t)i * 8;
  bf16x8 o;
#pragma unroll
  for (int j = 0; j < 8; ++j) o[j] = (bf16_t)p[j];
  *(bf16x8*)(out + (size_t)i * 8) = o;
}

// ---------------- weight transpose + cvt: W[k][n] f32 -> WT[n][k] bf16 ----------------
__global__ void wt_kernel(const float* __restrict__ w0, const float* __restrict__ w1,
                          const float* __restrict__ w2, const float* __restrict__ w3,
                          const float* __restrict__ w4, bf16_t* __restrict__ out) {
  __shared__ float tile[32][33];
  const float* Wsel = blockIdx.z == 0 ? w0 : blockIdx.z == 1 ? w1 :
                      blockIdx.z == 2 ? w2 : blockIdx.z == 3 ? w3 : w4;
  bf16_t* O = out + (size_t)blockIdx.z * EE * EE;
  int n0 = blockIdx.x * 32, k0 = blockIdx.y * 32;
  int tx = threadIdx.x & 31, ty = threadIdx.x >> 5;
#pragma unroll
  for (int i = 0; i < 4; ++i)
    tile[ty + i * 8][tx] = Wsel[(size_t)(k0 + ty + i * 8) * EE + n0 + tx];
  __syncthreads();
#pragma unroll
  for (int i = 0; i < 4; ++i)
    O[(size_t)(n0 + ty + i * 8) * EE + k0 + tx] = (bf16_t)tile[tx][ty + i * 8];
}

// ---------------- QKVG GEMM: 256x256 tile, BK=64, 8-phase pipelined schedule ----------------
// C[8192][4096] = A[8192][1024] @ Bt[4096][1024]^T, bf16 out into 4 regions (Q,K,Vt,G);
// V (widx==2) written transposed [B][H][D][S].
__global__ __launch_bounds__(512, 2) void gemm8p(const bf16_t* __restrict__ A,
                                                 const bf16_t* __restrict__ Bt,
                                                 bf16_t* __restrict__ Obase) {
  __shared__ bf16_t Al[2][2][128][64];  // [buf][row-half][row][col]
  __shared__ bf16_t Bl[2][2][128][64];
  // XCD-aware swizzle: 512 blocks, 8 XCDs; each XCD gets 4 contiguous M-rows (A panel L2-resident)
  const int id = blockIdx.x;
  const int swz = (id & 7) * 64 + (id >> 3);
  const int bx = swz >> 4, by = swz & 15;
  const int m0 = bx << 8, n0 = by << 8;
  const int tid = threadIdx.x, wv = tid >> 6, ln = tid & 63;
  const int wm = wv >> 2, wn = wv & 3;
  // staging: thread covers 16B chunk; one instr = 8KB = 64 rows x 128B
  const int sr = tid >> 3;                   // row 0..63 within instr group
  const int scs = (tid & 7) ^ (sr & 7);      // inverse-swizzled source chunk
  const bf16_t* Abase = A + ((size_t)(m0 + sr) << 10) + scs * 8;
  const bf16_t* Bbase = Bt + ((size_t)(n0 + sr) << 10) + scs * 8;

  f32x4 acc[8][4] = {};
  bf16x8 bfr[4][2];

#define STA(BUFI, H, J, KT) \
  gload16(Abase + (((H)*128 + (J)*64) << 10) + (KT)*64, &Al[BUFI][H][(J)*64 + wv * 8][0])
#define STB(BUFI, H, J, KT) \
  gload16(Bbase + (((H)*128 + (J)*64) << 10) + (KT)*64, &Bl[BUFI][H][(J)*64 + wv * 8][0])

#define PHASE(BUFI, MH, KK, LDB, STAGEC, WAITC) do {                           \
    bf16x8 af_[4];                                                             \
    _Pragma("unroll") for (int mi_ = 0; mi_ < 4; ++mi_) {                      \
      int ar_ = (MH)*64 + mi_*16 + (ln & 15);                                  \
      int ach_ = ((KK)*4 + (ln >> 4)) ^ (ar_ & 7);                             \
      af_[mi_] = *(const bf16x8*)&Al[BUFI][wm][ar_][ach_ * 8];                 \
    }                                                                          \
    if (LDB) {                                                                 \
      _Pragma("unroll") for (int ni_ = 0; ni_ < 4; ++ni_) {                    \
        int br_ = (wn & 1)*64 + ni_*16 + (ln & 15);                            \
        int bch_ = ((KK)*4 + (ln >> 4)) ^ (br_ & 7);                           \
        bfr[ni_][KK] = *(const bf16x8*)&Bl[BUFI][wn >> 1][br_][bch_ * 8];      \
      }                                                                        \
    }                                                                          \
    STAGEC;                                                                    \
    WAITC;                                                                     \
    __builtin_amdgcn_s_barrier();                                              \
    asm volatile("" ::: "memory");                                             \
    __builtin_amdgcn_s_setprio(1);                                             \
    _Pragma("unroll") for (int mi_ = 0; mi_ < 4; ++mi_)                        \
      _Pragma("unroll") for (int ni_ = 0; ni_ < 4; ++ni_)                      \
        acc[(MH)*4 + mi_][ni_] = __builtin_amdgcn_mfma_f32_16x16x32_bf16(      \
            af_[mi_], bfr[ni_][KK], acc[(MH)*4 + mi_][ni_], 0, 0, 0);          \
    __builtin_amdgcn_s_setprio(0);                                             \
    __builtin_amdgcn_s_barrier();                                              \
    asm volatile("" ::: "memory");                                             \
  } while (0)

  // ---- prologue: tile0 fully (8 loads) + tile1 A.i0 halves (2 loads)
  STA(0, 0, 0, 0); STA(0, 1, 0, 0); STA(0, 0, 1, 0); STA(0, 1, 1, 0);
  STB(0, 0, 0, 0); STB(0, 0, 1, 0); STB(0, 1, 0, 0); STB(0, 1, 1, 0);
  STA(1, 0, 0, 1); STA(1, 1, 0, 1);
  asm volatile("s_waitcnt vmcnt(2)" ::: "memory");  // tile0 landed; tile1.Ai0 in flight
  __builtin_amdgcn_s_barrier();
  asm volatile("" ::: "memory");

  for (int i = 0; i < 8; ++i) {
    const int to = 2 * i + 1;  // odd tile (buf1); even tile te=2i (buf0)
    // p1 (mh0,kk0) compute buf0; stage rest of tile 'to' -> buf1 (A.i1 freed prev p7/p8, B freed prev p5/p6)
    PHASE(0, 0, 0, 1,
          ({ STA(1, 0, 1, to); STA(1, 1, 1, to); STB(1, 0, 0, to); STB(1, 0, 1, to); }),
          ((void)0));
    // p2 (mh0,kk1): stage to.B.h1
    PHASE(0, 0, 1, 1, ({ STB(1, 1, 0, to); STB(1, 1, 1, to); }), ((void)0));
    // p3 (mh1,kk0): stage (te+2).A.i0 -> buf0 (A.i0 rows freed after p2)
    PHASE(0, 1, 0, 0, ({ if (i < 7) { STA(0, 0, 0, to + 1); STA(0, 1, 0, to + 1); } }), ((void)0));
    // p4 (mh1,kk1): checkpoint -> tile 'to' fully landed before p5 reads buf1
    PHASE(0, 1, 1, 0, ((void)0),
          ({ if (i < 7) { asm volatile("s_waitcnt vmcnt(2)" ::: "memory"); }
             else       { asm volatile("s_waitcnt vmcnt(0)" ::: "memory"); } }));
    // p5 (mh0,kk0) compute buf1; stage (te+2).A.i1 + B.h0 -> buf0 (freed after p4)
    PHASE(1, 0, 0, 1,
          ({ if (i < 7) { STA(0, 0, 1, to + 1); STA(0, 1, 1, to + 1);
                          STB(0, 0, 0, to + 1); STB(0, 0, 1, to + 1); } }),
          ((void)0));
    // p6 (mh0,kk1): stage (te+2).B.h1
    PHASE(1, 0, 1, 1, ({ if (i < 7) { STB(0, 1, 0, to + 1); STB(0, 1, 1, to + 1); } }), ((void)0));
    // p7 (mh1,kk0): stage (to+2).A.i0 -> buf1 (A.i0 rows freed after p6)
    PHASE(1, 1, 0, 0, ({ if (i < 7) { STA(1, 0, 0, to + 2); STA(1, 1, 0, to + 2); } }), ((void)0));
    // p8 (mh1,kk1): checkpoint -> tile te+2 fully landed before next-p1 reads buf0
    PHASE(1, 1, 1, 0, ((void)0),
          ({ if (i < 7) { asm volatile("s_waitcnt vmcnt(2)" ::: "memory"); }
             else       { asm volatile("s_waitcnt vmcnt(0)" ::: "memory"); } }));
  }
#undef PHASE
#undef STA
#undef STB

  // ---- epilogue: bf16 out, V region transposed
#pragma unroll
  for (int mi = 0; mi < 8; ++mi) {
#pragma unroll
    for (int ni = 0; ni < 4; ++ni) {
      int row = m0 + wm * 128 + mi * 16 + ((ln >> 4) << 2);  // + reg r
      int col = n0 + wn * 64 + ni * 16 + (ln & 15);
      int widx = col >> 10, ncol = col & 1023;
      bf16_t* W = Obase + (size_t)widx * MM * EE;
      if (widx == 2) {  // V: write transposed [B][H][D][S]
        int h = ncol >> 6, d = ncol & 63;
        int b = row >> 12, s = row & (SS - 1);
        bf16_t* p = W + (((size_t)b * HH + h) * DD + d) * SS + s;
#pragma unroll
        for (int r = 0; r < 4; ++r) p[r] = (bf16_t)acc[mi][ni][r];
      } else {
        bf16_t* p = W + (size_t)row * EE + ncol;
#pragma unroll
        for (int r = 0; r < 4; ++r) p[(size_t)r * EE] = (bf16_t)acc[mi][ni][r];
      }
    }
  }
}

// ---------------- final GEMM (m97-style 128x128, f32 out) ----------------
__global__ __launch_bounds__(256) void gemm_out(const bf16_t* __restrict__ A,
                                                const bf16_t* __restrict__ Bt,
                                                float* __restrict__ O) {
  __shared__ bf16_t Al[128 * 64];
  __shared__ bf16_t Bl[128 * 64];
  const int m0 = blockIdx.x * 128;
  const int n0 = blockIdx.y * 128;
  const int tid = threadIdx.x;
  const int wv = tid >> 6, ln = tid & 63;
  const int wm = wv >> 1, wn = wv & 1;
  f32x4 acc[4][4] = {};

  for (int k0 = 0; k0 < EE; k0 += 64) {
    __syncthreads();
#pragma unroll
    for (int i = 0; i < 4; ++i) {
      int slot = i * 256 + wv * 64 + ln;
      int r = slot >> 3, c = slot & 7;
      int cs = c ^ (r & 7);
      gload16(A + (size_t)(m0 + r) * EE + k0 + cs * 8, Al + (size_t)(i * 256 + wv * 64) * 8);
      gload16(Bt + (size_t)(n0 + r) * EE + k0 + cs * 8, Bl + (size_t)(i * 256 + wv * 64) * 8);
    }
    __syncthreads();
#pragma unroll
    for (int kk = 0; kk < 2; ++kk) {
      bf16x8 af[4], bfr[4];
#pragma unroll
      for (int mi = 0; mi < 4; ++mi) {
        int row = wm * 64 + mi * 16 + (ln & 15);
        int ch = (kk * 4 + (ln >> 4)) ^ (row & 7);
        af[mi] = *(const bf16x8*)(Al + row * 64 + ch * 8);
      }
#pragma unroll
      for (int ni = 0; ni < 4; ++ni) {
        int row = wn * 64 + ni * 16 + (ln & 15);
        int ch = (kk * 4 + (ln >> 4)) ^ (row & 7);
        bfr[ni] = *(const bf16x8*)(Bl + row * 64 + ch * 8);
      }
#pragma unroll
      for (int mi = 0; mi < 4; ++mi)
#pragma unroll
        for (int ni = 0; ni < 4; ++ni)
          acc[mi][ni] = __builtin_amdgcn_mfma_f32_16x16x32_bf16(af[mi], bfr[ni], acc[mi][ni], 0, 0, 0);
    }
  }

#pragma unroll
  for (int mi = 0; mi < 4; ++mi)
#pragma unroll
    for (int ni = 0; ni < 4; ++ni) {
      int row = m0 + wm * 64 + mi * 16 + ((ln >> 4) << 2);
      int col = n0 + wn * 64 + ni * 16 + (ln & 15);
#pragma unroll
      for (int r = 0; r < 4; ++r) O[(size_t)(row + r) * EE + col] = acc[mi][ni][r];
    }
}

// ---------------- RoPE in-place on Q and K (bf16), cos/sin f32 [S][64] ----------------
__global__ void rope_kernel(bf16_t* __restrict__ Q, bf16_t* __restrict__ Kt,
                            const float* __restrict__ cosp, const float* __restrict__ sinp) {
  int idx = blockIdx.x * 256 + threadIdx.x;  // MM*HH*4 threads
  int dg = (idx & 3) * 8;
  int h = (idx >> 2) & (HH - 1);
  int m = idx >> 6;
  if (m >= MM) return;
  int s = m & (SS - 1);
  size_t base = (size_t)m * EE + h * DD;
  float cl[8], sl[8], chv[8], shv[8];
#pragma unroll
  for (int j = 0; j < 8; ++j) {
    cl[j] = cosp[s * DD + dg + j];
    sl[j] = sinp[s * DD + dg + j];
    chv[j] = cosp[s * DD + 32 + dg + j];
    shv[j] = sinp[s * DD + 32 + dg + j];
  }
#pragma unroll
  for (int t = 0; t < 2; ++t) {
    bf16_t* P = t == 0 ? Q : Kt;
    bf16x8 lo = *(bf16x8*)(P + base + dg);
    bf16x8 hi = *(bf16x8*)(P + base + 32 + dg);
    bf16x8 olo, ohi;
#pragma unroll
    for (int j = 0; j < 8; ++j) {
      float ql = (float)lo[j], qh = (float)hi[j];
      olo[j] = (bf16_t)(ql * cl[j] - qh * sl[j]);
      ohi[j] = (bf16_t)(qh * chv[j] + ql * shv[j]);
    }
    *(bf16x8*)(P + base + dg) = olo;
    *(bf16x8*)(P + base + 32 + dg) = ohi;
  }
}

// ---------------- block-diagonal attention + fused sigmoid gate ----------------
// grid: B*nb*H blocks; block: 4 waves, wave handles 64 q-rows of the 256-row block.
__global__ __launch_bounds__(256) void attn_kernel(const bf16_t* __restrict__ Q,
                                                   const bf16_t* __restrict__ Kc,
                                                   const bf16_t* __restrict__ Vt,
                                                   const bf16_t* __restrict__ G,
                                                   bf16_t* __restrict__ AO) {
  __shared__ bf16_t Kl[64 * 64];
  __shared__ bf16_t Vl[64 * 64];
  __shared__ bf16_t Pl[4][64 * 64];
  const int bx = blockIdx.x;
  const int h = bx & 15, sb = (bx >> 4) & 15, b = bx >> 8;
  const int tid = threadIdx.x, wv = tid >> 6, ln = tid & 63;
  const int qrow0 = b * SS + sb * 256 + wv * 64;

  bf16x8 qf[4][2];
#pragma unroll
  for (int mi = 0; mi < 4; ++mi)
#pragma unroll
    for (int kk = 0; kk < 2; ++kk)
      qf[mi][kk] = *(const bf16x8*)(Q + (size_t)(qrow0 + mi * 16 + (ln & 15)) * EE +
                                    h * DD + kk * 32 + ((ln >> 4) << 3));

  f32x4 o[4][4] = {};
  float mr[4][4], lr[4][4];
#pragma unroll
  for (int i = 0; i < 4; ++i)
#pragma unroll
    for (int r = 0; r < 4; ++r) { mr[i][r] = -1e30f; lr[i][r] = 0.f; }

  for (int kc = 0; kc < 4; ++kc) {
    __syncthreads();
    const int krow0 = b * SS + sb * 256 + kc * 64;
#pragma unroll
    for (int i = 0; i < 2; ++i) {
      int slot = i * 256 + wv * 64 + ln;
      int r = slot >> 3, c = slot & 7, cs = c ^ (r & 7);
      gload16(Kc + (size_t)(krow0 + r) * EE + h * DD + cs * 8, Kl + (i * 256 + wv * 64) * 8);
      gload16(Vt + (((size_t)b * HH + h) * DD + r) * SS + sb * 256 + kc * 64 + cs * 8,
              Vl + (i * 256 + wv * 64) * 8);
    }
    __syncthreads();

    f32x4 sc[4][4] = {};
#pragma unroll
    for (int kk = 0; kk < 2; ++kk) {
      bf16x8 kf[4];
#pragma unroll
      for (int ni = 0; ni < 4; ++ni) {
        int row = ni * 16 + (ln & 15);
        int ch = (kk * 4 + (ln >> 4)) ^ (row & 7);
        kf[ni] = *(const bf16x8*)(Kl + row * 64 + ch * 8);
      }
#pragma unroll
      for (int mi = 0; mi < 4; ++mi)
#pragma unroll
        for (int ni = 0; ni < 4; ++ni)
          sc[mi][ni] = __builtin_amdgcn_mfma_f32_16x16x32_bf16(qf[mi][kk], kf[ni], sc[mi][ni], 0, 0, 0);
    }
#pragma unroll
    for (int mi = 0; mi < 4; ++mi)
#pragma unroll
      for (int ni = 0; ni < 4; ++ni) sc[mi][ni] *= 0.125f;

#pragma unroll
    for (int mi = 0; mi < 4; ++mi) {
#pragma unroll
      for (int r = 0; r < 4; ++r) {
        float mx = fmaxf(fmaxf(sc[mi][0][r], sc[mi][1][r]), fmaxf(sc[mi][2][r], sc[mi][3][r]));
#pragma unroll
        for (int d = 1; d < 16; d <<= 1) mx = fmaxf(mx, __shfl_xor(mx, d));
        float mn = fmaxf(mr[mi][r], mx);
        float scal = __expf(mr[mi][r] - mn);
        mr[mi][r] = mn;
        float rs = 0.f;
#pragma unroll
        for (int ni = 0; ni < 4; ++ni) {
          float p = __expf(sc[mi][ni][r] - mn);
          sc[mi][ni][r] = p;
          rs += p;
        }
#pragma unroll
        for (int d = 1; d < 16; d <<= 1) rs += __shfl_xor(rs, d);
        lr[mi][r] = lr[mi][r] * scal + rs;
#pragma unroll
        for (int nd = 0; nd < 4; ++nd) o[mi][nd][r] *= scal;
      }
    }

    bf16_t* P = Pl[wv];
#pragma unroll
    for (int mi = 0; mi < 4; ++mi)
#pragma unroll
      for (int ni = 0; ni < 4; ++ni)
#pragma unroll
        for (int r = 0; r < 4; ++r) {
          int row = mi * 16 + ((ln >> 4) << 2) + r;
          int col = ni * 16 + (ln & 15);
          P[row * 64 + (col ^ ((row & 7) << 3))] = (bf16_t)sc[mi][ni][r];
        }
#pragma unroll
    for (int kk = 0; kk < 2; ++kk) {
      bf16x8 pf[4], vf[4];
#pragma unroll
      for (int mi = 0; mi < 4; ++mi) {
        int row = mi * 16 + (ln & 15);
        int ch = (kk * 4 + (ln >> 4)) ^ (row & 7);
        pf[mi] = *(const bf16x8*)(P + row * 64 + ch * 8);
      }
#pragma unroll
      for (int nd = 0; nd < 4; ++nd) {
        int row = nd * 16 + (ln & 15);
        int ch = (kk * 4 + (ln >> 4)) ^ (row & 7);
        vf[nd] = *(const bf16x8*)(Vl + row * 64 + ch * 8);
      }
#pragma unroll
      for (int mi = 0; mi < 4; ++mi)
#pragma unroll
        for (int nd = 0; nd < 4; ++nd)
          o[mi][nd] = __builtin_amdgcn_mfma_f32_16x16x32_bf16(pf[mi], vf[nd], o[mi][nd], 0, 0, 0);
    }
  }

#pragma unroll
  for (int mi = 0; mi < 4; ++mi)
#pragma unroll
    for (int nd = 0; nd < 4; ++nd)
#pragma unroll
      for (int r = 0; r < 4; ++r) {
        int m = qrow0 + mi * 16 + ((ln >> 4) << 2) + r;
        int col = h * DD + nd * 16 + (ln & 15);
        float gv = (float)G[(size_t)m * EE + col];
        float sig = 1.f / (1.f + __expf(-gv));
        AO[(size_t)m * EE + col] = (bf16_t)((o[mi][nd][r] / lr[mi][r]) * sig);
      }
}

extern "C" void kernel_launch(void* const* d_in, const int* in_sizes, int n_in,
                              void* d_out, int out_size, void* d_ws, size_t ws_size,
                              hipStream_t stream) {
  const float* x = (const float*)d_in[0];
  const float* Wq = (const float*)d_in[1];
  const float* Wk = (const float*)d_in[2];
  const float* Wv = (const float*)d_in[3];
  const float* Wg = (const float*)d_in[4];
  const float* Wo = (const float*)d_in[5];
  const float* cosp = (const float*)d_in[6];
  const float* sinp = (const float*)d_in[7];
  float* out = (float*)d_out;

  char* ws = (char*)d_ws;
  bf16_t* XB = (bf16_t*)(ws);                       // 16MB: x bf16; reused as gated AO
  bf16_t* WT = (bf16_t*)(ws + (16ll << 20));        // 10MB: [5][1024][1024] W^T bf16 (q,k,v,g,o)
  bf16_t* QB = (bf16_t*)(ws + (26ll << 20));        // 16MB: Q
  bf16_t* KB = (bf16_t*)(ws + (42ll << 20));        // 16MB: K
  bf16_t* VT = (bf16_t*)(ws + (58ll << 20));        // 16MB: V transposed [B][H][D][S]
  bf16_t* GB = (bf16_t*)(ws + (74ll << 20));        // 16MB: gate
  bf16_t* AO = XB;                                  // gated attention output reuses XB region

  const int n8 = MM * EE / 8;  // 1048576
  cvt_kernel<<<n8 / 256, 256, 0, stream>>>(x, XB, n8);
  wt_kernel<<<dim3(32, 32, 5), 256, 0, stream>>>(Wq, Wk, Wv, Wg, Wo, WT);
  gemm8p<<<512, 512, 0, stream>>>(XB, WT, QB);
  rope_kernel<<<(MM * HH * 4) / 256, 256, 0, stream>>>(QB, KB, cosp, sinp);
  attn_kernel<<<BB * (SS / 256) * HH, 256, 0, stream>>>(QB, KB, VT, GB, AO);
  gemm_out<<<dim3(MM / 128, EE / 128), 256, 0, stream>>>(AO, WT + (size_t)4 * EE * EE, out);
}

// Round 3
// 178.846 us; speedup vs baseline: 1.0969x; 1.0969x over previous
//
#include <hip/hip_runtime.h>
#include <hip/hip_bf16.h>
#include <stdint.h>

typedef __bf16 bf16_t;
typedef __bf16 bf16x8 __attribute__((ext_vector_type(8)));
typedef float f32x4 __attribute__((ext_vector_type(4)));

#define DEVI __device__ __forceinline__

constexpr int BB = 2;       // batch
constexpr int SS = 4096;    // seq
constexpr int EE = 1024;    // embed
constexpr int HH = 16;      // heads
constexpr int DD = 64;      // head dim
constexpr int MM = BB * SS; // 8192 token rows

// async global->LDS, 16B per lane; LDS dest must be wave-uniform base (HW adds lane*16)
DEVI void gload16(const void* g, void* l) {
  __builtin_amdgcn_global_load_lds(
      (const __attribute__((address_space(1))) void*)g,
      (__attribute__((address_space(3))) void*)l, 16, 0, 0);
}

// ---------------- f32 -> bf16 convert (vectorized 8/thread) ----------------
__global__ void cvt_kernel(const float* __restrict__ in, bf16_t* __restrict__ out, int n8) {
  int i = blockIdx.x * 256 + threadIdx.x;
  if (i >= n8) return;
  const float* p = in + (size_t)i * 8;
  bf16x8 o;
#pragma unroll
  for (int j = 0; j < 8; ++j) o[j] = (bf16_t)p[j];
  *(bf16x8*)(out + (size_t)i * 8) = o;
}

// ---------------- weight transpose + cvt: W[k][n] f32 -> WT[n][k] bf16 ----------------
__global__ void wt_kernel(const float* __restrict__ w0, const float* __restrict__ w1,
                          const float* __restrict__ w2, const float* __restrict__ w3,
                          const float* __restrict__ w4, bf16_t* __restrict__ out) {
  __shared__ float tile[32][33];
  const float* Wsel = blockIdx.z == 0 ? w0 : blockIdx.z == 1 ? w1 :
                      blockIdx.z == 2 ? w2 : blockIdx.z == 3 ? w3 : w4;
  bf16_t* O = out + (size_t)blockIdx.z * EE * EE;
  int n0 = blockIdx.x * 32, k0 = blockIdx.y * 32;
  int tx = threadIdx.x & 31, ty = threadIdx.x >> 5;
#pragma unroll
  for (int i = 0; i < 4; ++i)
    tile[ty + i * 8][tx] = Wsel[(size_t)(k0 + ty + i * 8) * EE + n0 + tx];
  __syncthreads();
#pragma unroll
  for (int i = 0; i < 4; ++i)
    O[(size_t)(n0 + ty + i * 8) * EE + k0 + tx] = (bf16_t)tile[tx][ty + i * 8];
}

// ---------------- QKVG GEMM: 256x256 tile, BK=64, 8-phase, vmcnt(6) pipeline ----------------
// C[8192][4096] = A[8192][1024] @ Bt[4096][1024]^T, bf16 out into 4 regions (Q,K,Vt,G).
// Q/K regions get RoPE applied in-register in the epilogue; V written transposed [B][H][D][S].
__global__ __launch_bounds__(512, 2) void gemm8p(const bf16_t* __restrict__ A,
                                                 const bf16_t* __restrict__ Bt,
                                                 bf16_t* __restrict__ Obase,
                                                 const float* __restrict__ cosp,
                                                 const float* __restrict__ sinp) {
  __shared__ bf16_t Al[2][2][128][64];  // [buf][row-half][row][col]
  __shared__ bf16_t Bl[2][2][128][64];
  const int id = blockIdx.x;
  const int swz = (id & 7) * 64 + (id >> 3);  // XCD-aware: 512 blocks, 8 XCDs
  const int bx = swz >> 4, by = swz & 15;
  const int m0 = bx << 8, n0 = by << 8;
  const int tid = threadIdx.x, wv = tid >> 6, ln = tid & 63;
  const int wm = wv >> 2, wn = wv & 3;
  const int sr = tid >> 3;                   // staging row within instr group
  const int scs = (tid & 7) ^ (sr & 7);      // inverse-swizzled source chunk
  const bf16_t* Abase = A + ((size_t)(m0 + sr) << 10) + scs * 8;
  const bf16_t* Bbase = Bt + ((size_t)(n0 + sr) << 10) + scs * 8;

  f32x4 acc[8][4] = {};
  bf16x8 bfr[4][2];

#define STA(BUFI, H, J, KT) \
  gload16(Abase + (((H)*128 + (J)*64) << 10) + (KT)*64, &Al[BUFI][H][(J)*64 + wv * 8][0])
#define STB(BUFI, H, J, KT) \
  gload16(Bbase + (((H)*128 + (J)*64) << 10) + (KT)*64, &Bl[BUFI][H][(J)*64 + wv * 8][0])
#define STB_ALL(BUFI, KT) do { STB(BUFI,0,0,KT); STB(BUFI,0,1,KT); STB(BUFI,1,0,KT); STB(BUFI,1,1,KT); } while (0)

#define PHASE(BUFI, MH, KK, LDB, STAGEC, WAITC) do {                           \
    bf16x8 af_[4];                                                             \
    _Pragma("unroll") for (int mi_ = 0; mi_ < 4; ++mi_) {                      \
      int ar_ = (MH)*64 + mi_*16 + (ln & 15);                                  \
      int ach_ = ((KK)*4 + (ln >> 4)) ^ (ar_ & 7);                             \
      af_[mi_] = *(const bf16x8*)&Al[BUFI][wm][ar_][ach_ * 8];                 \
    }                                                                          \
    if (LDB) {                                                                 \
      _Pragma("unroll") for (int ni_ = 0; ni_ < 4; ++ni_) {                    \
        int br_ = (wn & 1)*64 + ni_*16 + (ln & 15);                            \
        int bch_ = ((KK)*4 + (ln >> 4)) ^ (br_ & 7);                           \
        bfr[ni_][KK] = *(const bf16x8*)&Bl[BUFI][wn >> 1][br_][bch_ * 8];      \
      }                                                                        \
    }                                                                          \
    STAGEC;                                                                    \
    WAITC;                                                                     \
    __builtin_amdgcn_s_barrier();                                              \
    asm volatile("s_waitcnt lgkmcnt(0)" ::: "memory");                         \
    __builtin_amdgcn_sched_barrier(0);                                         \
    __builtin_amdgcn_s_setprio(1);                                             \
    _Pragma("unroll") for (int mi_ = 0; mi_ < 4; ++mi_)                        \
      _Pragma("unroll") for (int ni_ = 0; ni_ < 4; ++ni_)                      \
        acc[(MH)*4 + mi_][ni_] = __builtin_amdgcn_mfma_f32_16x16x32_bf16(      \
            af_[mi_], bfr[ni_][KK], acc[(MH)*4 + mi_][ni_], 0, 0, 0);          \
    __builtin_amdgcn_s_setprio(0);                                             \
    __builtin_amdgcn_s_barrier();                                              \
    asm volatile("" ::: "memory");                                             \
  } while (0)

  // ---- prologue: tile0 full (8) + tile1 A.J0+B (6); wait tile0, keep 6 in flight
  STA(0, 0, 0, 0); STA(0, 1, 0, 0);
  STB_ALL(0, 0);
  STA(0, 0, 1, 0); STA(0, 1, 1, 0);
  STA(1, 0, 0, 1); STA(1, 1, 0, 1);
  STB_ALL(1, 1);
  asm volatile("s_waitcnt vmcnt(6)" ::: "memory");
  __builtin_amdgcn_s_barrier();
  asm volatile("" ::: "memory");

#pragma unroll 1
  for (int i = 0; i < 7; ++i) {
    const int to = 2 * i + 1;
    // p1 (buf0,mh0,kk0): stage to.A.J1 (buf1.A.J1 freed prev p8)
    PHASE(0, 0, 0, 1, ({ STA(1, 0, 1, to); STA(1, 1, 1, to); }), ((void)0));
    // p2 (buf0,mh0,kk1)
    PHASE(0, 0, 1, 1, ((void)0), ((void)0));
    // p3 (buf0,mh1,kk0): stage (te+2).A.J0 + B (buf0 J0/B freed after p2)
    PHASE(0, 1, 0, 0, ({ STA(0, 0, 0, to + 1); STA(0, 1, 0, to + 1); STB_ALL(0, to + 1); }),
          ((void)0));
    // p4 (buf0,mh1,kk1): tile 'to' (oldest 8) landed; 6 stay in flight
    PHASE(0, 1, 1, 0, ((void)0), ({ asm volatile("s_waitcnt vmcnt(6)" ::: "memory"); }));
    // p5 (buf1,mh0,kk0): stage (te+2).A.J1 (buf0.A.J1 freed after p4)
    PHASE(1, 0, 0, 1, ({ STA(0, 0, 1, to + 1); STA(0, 1, 1, to + 1); }), ((void)0));
    // p6 (buf1,mh0,kk1)
    PHASE(1, 0, 1, 1, ((void)0), ((void)0));
    // p7 (buf1,mh1,kk0): stage (to+2).A.J0 + B (buf1 J0/B freed after p6)
    PHASE(1, 1, 0, 0, ({ STA(1, 0, 0, to + 2); STA(1, 1, 0, to + 2); STB_ALL(1, to + 2); }),
          ((void)0));
    // p8 (buf1,mh1,kk1): tile te+2 (oldest 8) landed
    PHASE(1, 1, 1, 0, ((void)0), ({ asm volatile("s_waitcnt vmcnt(6)" ::: "memory"); }));
  }
  // ---- peeled last iteration (i=7, to=15): no further staging
  PHASE(0, 0, 0, 1, ({ STA(1, 0, 1, 15); STA(1, 1, 1, 15); }), ((void)0));
  PHASE(0, 0, 1, 1, ((void)0), ((void)0));
  PHASE(0, 1, 0, 0, ((void)0), ((void)0));
  PHASE(0, 1, 1, 0, ((void)0), ({ asm volatile("s_waitcnt vmcnt(0)" ::: "memory"); }));
  PHASE(1, 0, 0, 1, ((void)0), ((void)0));
  PHASE(1, 0, 1, 1, ((void)0), ((void)0));
  PHASE(1, 1, 0, 0, ((void)0), ((void)0));
  PHASE(1, 1, 1, 0, ((void)0), ((void)0));
#undef PHASE
#undef STA
#undef STB
#undef STB_ALL

  // ---- epilogue: widx uniform per block (by>>2). Q/K: fused RoPE. V: transposed.
  const int widx = n0 >> 10;
  const int cb = (n0 & 1023) + wn * 64;  // region-local col base (head-aligned)
  bf16_t* W = Obase + (size_t)widx * MM * EE;
  if (widx <= 1) {
    // RoPE in-register: d = ni*16+(ln&15); pair element is acc[mi][ni^2] (same lane)
#pragma unroll
    for (int mi = 0; mi < 8; ++mi) {
#pragma unroll
      for (int r = 0; r < 4; ++r) {
        int row = m0 + wm * 128 + mi * 16 + ((ln >> 4) << 2) + r;
        int s = row & (SS - 1);
        float cv[4], sv[4];
#pragma unroll
        for (int ni = 0; ni < 4; ++ni) {
          int d = ni * 16 + (ln & 15);
          cv[ni] = cosp[s * DD + d];
          sv[ni] = sinp[s * DD + d];
        }
#pragma unroll
        for (int ni = 0; ni < 4; ++ni) {
          float v = acc[mi][ni][r], p = acc[mi][ni ^ 2][r];
          float o = v * cv[ni] + (ni < 2 ? -p : p) * sv[ni];
          W[(size_t)row * EE + cb + ni * 16 + (ln & 15)] = (bf16_t)o;
        }
      }
    }
  } else if (widx == 2) {
#pragma unroll
    for (int mi = 0; mi < 8; ++mi)
#pragma unroll
      for (int ni = 0; ni < 4; ++ni) {
        int row = m0 + wm * 128 + mi * 16 + ((ln >> 4) << 2);
        int ncol = cb + ni * 16 + (ln & 15);
        int h = ncol >> 6, d = ncol & 63;
        int b = row >> 12, s = row & (SS - 1);
        bf16_t* p = W + (((size_t)b * HH + h) * DD + d) * SS + s;
#pragma unroll
        for (int r = 0; r < 4; ++r) p[r] = (bf16_t)acc[mi][ni][r];
      }
  } else {
#pragma unroll
    for (int mi = 0; mi < 8; ++mi)
#pragma unroll
      for (int ni = 0; ni < 4; ++ni) {
        int row = m0 + wm * 128 + mi * 16 + ((ln >> 4) << 2);
        int ncol = cb + ni * 16 + (ln & 15);
        bf16_t* p = W + (size_t)row * EE + ncol;
#pragma unroll
        for (int r = 0; r < 4; ++r) p[(size_t)r * EE] = (bf16_t)acc[mi][ni][r];
      }
  }
}

// ---------------- final GEMM (m97-style 128x128, f32 out) ----------------
__global__ __launch_bounds__(256) void gemm_out(const bf16_t* __restrict__ A,
                                                const bf16_t* __restrict__ Bt,
                                                float* __restrict__ O) {
  __shared__ bf16_t Al[128 * 64];
  __shared__ bf16_t Bl[128 * 64];
  const int m0 = blockIdx.x * 128;
  const int n0 = blockIdx.y * 128;
  const int tid = threadIdx.x;
  const int wv = tid >> 6, ln = tid & 63;
  const int wm = wv >> 1, wn = wv & 1;
  f32x4 acc[4][4] = {};

  for (int k0 = 0; k0 < EE; k0 += 64) {
    __syncthreads();
#pragma unroll
    for (int i = 0; i < 4; ++i) {
      int slot = i * 256 + wv * 64 + ln;
      int r = slot >> 3, c = slot & 7;
      int cs = c ^ (r & 7);
      gload16(A + (size_t)(m0 + r) * EE + k0 + cs * 8, Al + (size_t)(i * 256 + wv * 64) * 8);
      gload16(Bt + (size_t)(n0 + r) * EE + k0 + cs * 8, Bl + (size_t)(i * 256 + wv * 64) * 8);
    }
    __syncthreads();
#pragma unroll
    for (int kk = 0; kk < 2; ++kk) {
      bf16x8 af[4], bfr[4];
#pragma unroll
      for (int mi = 0; mi < 4; ++mi) {
        int row = wm * 64 + mi * 16 + (ln & 15);
        int ch = (kk * 4 + (ln >> 4)) ^ (row & 7);
        af[mi] = *(const bf16x8*)(Al + row * 64 + ch * 8);
      }
#pragma unroll
      for (int ni = 0; ni < 4; ++ni) {
        int row = wn * 64 + ni * 16 + (ln & 15);
        int ch = (kk * 4 + (ln >> 4)) ^ (row & 7);
        bfr[ni] = *(const bf16x8*)(Bl + row * 64 + ch * 8);
      }
#pragma unroll
      for (int mi = 0; mi < 4; ++mi)
#pragma unroll
        for (int ni = 0; ni < 4; ++ni)
          acc[mi][ni] = __builtin_amdgcn_mfma_f32_16x16x32_bf16(af[mi], bfr[ni], acc[mi][ni], 0, 0, 0);
    }
  }

#pragma unroll
  for (int mi = 0; mi < 4; ++mi)
#pragma unroll
    for (int ni = 0; ni < 4; ++ni) {
      int row = m0 + wm * 64 + mi * 16 + ((ln >> 4) << 2);
      int col = n0 + wn * 64 + ni * 16 + (ln & 15);
#pragma unroll
      for (int r = 0; r < 4; ++r) O[(size_t)(row + r) * EE + col] = acc[mi][ni][r];
    }
}

// ---------------- block-diagonal attention + fused sigmoid gate ----------------
// grid: B*nb*H blocks; 4 waves; K/V double-buffered, prefetch kc+1 before compute kc.
__global__ __launch_bounds__(256) void attn_kernel(const bf16_t* __restrict__ Q,
                                                   const bf16_t* __restrict__ Kc,
                                                   const bf16_t* __restrict__ Vt,
                                                   const bf16_t* __restrict__ G,
                                                   bf16_t* __restrict__ AO) {
  __shared__ bf16_t Kl[2][64 * 64];
  __shared__ bf16_t Vl[2][64 * 64];
  __shared__ bf16_t Pl[4][64 * 64];
  const int bx = blockIdx.x;
  const int h = bx & 15, sb = (bx >> 4) & 15, b = bx >> 8;
  const int tid = threadIdx.x, wv = tid >> 6, ln = tid & 63;
  const int qrow0 = b * SS + sb * 256 + wv * 64;

  bf16x8 qf[4][2];
#pragma unroll
  for (int mi = 0; mi < 4; ++mi)
#pragma unroll
    for (int kk = 0; kk < 2; ++kk)
      qf[mi][kk] = *(const bf16x8*)(Q + (size_t)(qrow0 + mi * 16 + (ln & 15)) * EE +
                                    h * DD + kk * 32 + ((ln >> 4) << 3));

  f32x4 o[4][4] = {};
  float mr[4][4], lr[4][4];
#pragma unroll
  for (int i = 0; i < 4; ++i)
#pragma unroll
    for (int r = 0; r < 4; ++r) { mr[i][r] = -1e30f; lr[i][r] = 0.f; }

#define STAGE_KV(KC, BI) do {                                                        \
    const int krow0_ = b * SS + sb * 256 + (KC) * 64;                                \
    _Pragma("unroll") for (int i_ = 0; i_ < 2; ++i_) {                               \
      int slot_ = i_ * 256 + wv * 64 + ln;                                           \
      int r_ = slot_ >> 3, c_ = slot_ & 7, cs_ = c_ ^ (r_ & 7);                      \
      gload16(Kc + (size_t)(krow0_ + r_) * EE + h * DD + cs_ * 8,                    \
              &Kl[BI][(i_ * 256 + wv * 64) * 8]);                                    \
      gload16(Vt + (((size_t)b * HH + h) * DD + r_) * SS + sb * 256 + (KC) * 64 +    \
                  cs_ * 8,                                                           \
              &Vl[BI][(i_ * 256 + wv * 64) * 8]);                                    \
    }                                                                                \
  } while (0)

  STAGE_KV(0, 0);
  __syncthreads();

  for (int kc = 0; kc < 4; ++kc) {
    const int cur = kc & 1;
    if (kc < 3) STAGE_KV(kc + 1, cur ^ 1);  // prefetch; drained by end-of-iter sync

    f32x4 sc[4][4] = {};
    __builtin_amdgcn_s_setprio(1);
#pragma unroll
    for (int kk = 0; kk < 2; ++kk) {
      bf16x8 kf[4];
#pragma unroll
      for (int ni = 0; ni < 4; ++ni) {
        int row = ni * 16 + (ln & 15);
        int ch = (kk * 4 + (ln >> 4)) ^ (row & 7);
        kf[ni] = *(const bf16x8*)(&Kl[cur][row * 64 + ch * 8]);
      }
#pragma unroll
      for (int mi = 0; mi < 4; ++mi)
#pragma unroll
        for (int ni = 0; ni < 4; ++ni)
          sc[mi][ni] = __builtin_amdgcn_mfma_f32_16x16x32_bf16(qf[mi][kk], kf[ni], sc[mi][ni], 0, 0, 0);
    }
    __builtin_amdgcn_s_setprio(0);
#pragma unroll
    for (int mi = 0; mi < 4; ++mi)
#pragma unroll
      for (int ni = 0; ni < 4; ++ni) sc[mi][ni] *= 0.125f;

#pragma unroll
    for (int mi = 0; mi < 4; ++mi) {
#pragma unroll
      for (int r = 0; r < 4; ++r) {
        float mx = fmaxf(fmaxf(sc[mi][0][r], sc[mi][1][r]), fmaxf(sc[mi][2][r], sc[mi][3][r]));
#pragma unroll
        for (int d = 1; d < 16; d <<= 1) mx = fmaxf(mx, __shfl_xor(mx, d));
        float mn = fmaxf(mr[mi][r], mx);
        float scal = __expf(mr[mi][r] - mn);
        mr[mi][r] = mn;
        float rs = 0.f;
#pragma unroll
        for (int ni = 0; ni < 4; ++ni) {
          float p = __expf(sc[mi][ni][r] - mn);
          sc[mi][ni][r] = p;
          rs += p;
        }
#pragma unroll
        for (int d = 1; d < 16; d <<= 1) rs += __shfl_xor(rs, d);
        lr[mi][r] = lr[mi][r] * scal + rs;
#pragma unroll
        for (int nd = 0; nd < 4; ++nd) o[mi][nd][r] *= scal;
      }
    }

    bf16_t* P = Pl[wv];
#pragma unroll
    for (int mi = 0; mi < 4; ++mi)
#pragma unroll
      for (int ni = 0; ni < 4; ++ni)
#pragma unroll
        for (int r = 0; r < 4; ++r) {
          int row = mi * 16 + ((ln >> 4) << 2) + r;
          int col = ni * 16 + (ln & 15);
          P[row * 64 + (col ^ ((row & 7) << 3))] = (bf16_t)sc[mi][ni][r];
        }
    __builtin_amdgcn_s_setprio(1);
#pragma unroll
    for (int kk = 0; kk < 2; ++kk) {
      bf16x8 pf[4], vf[4];
#pragma unroll
      for (int mi = 0; mi < 4; ++mi) {
        int row = mi * 16 + (ln & 15);
        int ch = (kk * 4 + (ln >> 4)) ^ (row & 7);
        pf[mi] = *(const bf16x8*)(P + row * 64 + ch * 8);
      }
#pragma unroll
      for (int nd = 0; nd < 4; ++nd) {
        int row = nd * 16 + (ln & 15);
        int ch = (kk * 4 + (ln >> 4)) ^ (row & 7);
        vf[nd] = *(const bf16x8*)(&Vl[cur][row * 64 + ch * 8]);
      }
#pragma unroll
      for (int mi = 0; mi < 4; ++mi)
#pragma unroll
        for (int nd = 0; nd < 4; ++nd)
          o[mi][nd] = __builtin_amdgcn_mfma_f32_16x16x32_bf16(pf[mi], vf[nd], o[mi][nd], 0, 0, 0);
    }
    __builtin_amdgcn_s_setprio(0);
    __syncthreads();  // drains prefetch vmcnt + LDS reuse fence
  }
#undef STAGE_KV

#pragma unroll
  for (int mi = 0; mi < 4; ++mi)
#pragma unroll
    for (int nd = 0; nd < 4; ++nd)
#pragma unroll
      for (int r = 0; r < 4; ++r) {
        int m = qrow0 + mi * 16 + ((ln >> 4) << 2) + r;
        int col = h * DD + nd * 16 + (ln & 15);
        float gv = (float)G[(size_t)m * EE + col];
        float sig = 1.f / (1.f + __expf(-gv));
        AO[(size_t)m * EE + col] = (bf16_t)((o[mi][nd][r] / lr[mi][r]) * sig);
      }
}

extern "C" void kernel_launch(void* const* d_in, const int* in_sizes, int n_in,
                              void* d_out, int out_size, void* d_ws, size_t ws_size,
                              hipStream_t stream) {
  const float* x = (const float*)d_in[0];
  const float* Wq = (const float*)d_in[1];
  const float* Wk = (const float*)d_in[2];
  const float* Wv = (const float*)d_in[3];
  const float* Wg = (const float*)d_in[4];
  const float* Wo = (const float*)d_in[5];
  const float* cosp = (const float*)d_in[6];
  const float* sinp = (const float*)d_in[7];
  float* out = (float*)d_out;

  char* ws = (char*)d_ws;
  bf16_t* XB = (bf16_t*)(ws);                       // 16MB: x bf16; reused as gated AO
  bf16_t* WT = (bf16_t*)(ws + (16ll << 20));        // 10MB: [5][1024][1024] W^T bf16 (q,k,v,g,o)
  bf16_t* QB = (bf16_t*)(ws + (26ll << 20));        // 16MB: Q (roped)
  bf16_t* KB = (bf16_t*)(ws + (42ll << 20));        // 16MB: K (roped)
  bf16_t* VT = (bf16_t*)(ws + (58ll << 20));        // 16MB: V transposed [B][H][D][S]
  bf16_t* GB = (bf16_t*)(ws + (74ll << 20));        // 16MB: gate
  bf16_t* AO = XB;                                  // gated attention output reuses XB region

  const int n8 = MM * EE / 8;  // 1048576
  cvt_kernel<<<n8 / 256, 256, 0, stream>>>(x, XB, n8);
  wt_kernel<<<dim3(32, 32, 5), 256, 0, stream>>>(Wq, Wk, Wv, Wg, Wo, WT);
  gemm8p<<<512, 512, 0, stream>>>(XB, WT, QB, cosp, sinp);
  attn_kernel<<<BB * (SS / 256) * HH, 256, 0, stream>>>(QB, KB, VT, GB, AO);
  gemm_out<<<dim3(MM / 128, EE / 128), 256, 0, stream>>>(AO, WT + (size_t)4 * EE * EE, out);
}

// Round 4
// 177.070 us; speedup vs baseline: 1.1079x; 1.0100x over previous
//
#include <hip/hip_runtime.h>
#include <hip/hip_bf16.h>
#include <stdint.h>

typedef __bf16 bf16_t;
typedef __bf16 bf16x8 __attribute__((ext_vector_type(8)));
typedef float f32x4 __attribute__((ext_vector_type(4)));

#define DEVI __device__ __forceinline__

constexpr int BB = 2;       // batch
constexpr int SS = 4096;    // seq
constexpr int EE = 1024;    // embed
constexpr int HH = 16;      // heads
constexpr int DD = 64;      // head dim
constexpr int MM = BB * SS; // 8192 token rows

// async global->LDS, 16B per lane; LDS dest must be wave-uniform base (HW adds lane*16)
DEVI void gload16(const void* g, void* l) {
  __builtin_amdgcn_global_load_lds(
      (const __attribute__((address_space(1))) void*)g,
      (__attribute__((address_space(3))) void*)l, 16, 0, 0);
}

// ---------------- f32 -> bf16 convert (vectorized 8/thread) ----------------
__global__ void cvt_kernel(const float* __restrict__ in, bf16_t* __restrict__ out, int n8) {
  int i = blockIdx.x * 256 + threadIdx.x;
  if (i >= n8) return;
  const float* p = in + (size_t)i * 8;
  bf16x8 o;
#pragma unroll
  for (int j = 0; j < 8; ++j) o[j] = (bf16_t)p[j];
  *(bf16x8*)(out + (size_t)i * 8) = o;
}

// ---------------- weight transpose + cvt: W[k][n] f32 -> WT[n][k] bf16 ----------------
__global__ void wt_kernel(const float* __restrict__ w0, const float* __restrict__ w1,
                          const float* __restrict__ w2, const float* __restrict__ w3,
                          const float* __restrict__ w4, bf16_t* __restrict__ out) {
  __shared__ float tile[32][33];
  const float* Wsel = blockIdx.z == 0 ? w0 : blockIdx.z == 1 ? w1 :
                      blockIdx.z == 2 ? w2 : blockIdx.z == 3 ? w3 : w4;
  bf16_t* O = out + (size_t)blockIdx.z * EE * EE;
  int n0 = blockIdx.x * 32, k0 = blockIdx.y * 32;
  int tx = threadIdx.x & 31, ty = threadIdx.x >> 5;
#pragma unroll
  for (int i = 0; i < 4; ++i)
    tile[ty + i * 8][tx] = Wsel[(size_t)(k0 + ty + i * 8) * EE + n0 + tx];
  __syncthreads();
#pragma unroll
  for (int i = 0; i < 4; ++i)
    O[(size_t)(n0 + ty + i * 8) * EE + k0 + tx] = (bf16_t)tile[tx][ty + i * 8];
}

// ---------------- QKVG GEMM: 256x256 tile, BK=64, 8-phase, even-rhythm staging ----------------
// C[8192][4096] = A[8192][1024] @ Bt[4096][1024]^T, bf16 out into 4 regions (Q,K,Vt,G).
// Q/K regions get RoPE applied in-register in the epilogue; V written transposed [B][H][D][S].
// Staging: exactly 2 global_load_lds per phase (one half-tile); counted vmcnt(4) at p4/p8.
__global__ __launch_bounds__(512, 2) void gemm8p(const bf16_t* __restrict__ A,
                                                 const bf16_t* __restrict__ Bt,
                                                 bf16_t* __restrict__ Obase,
                                                 const float* __restrict__ cosp,
                                                 const float* __restrict__ sinp) {
  __shared__ bf16_t Al[2][2][128][64];  // [buf][row-half][row][col]
  __shared__ bf16_t Bl[2][2][128][64];
  const int id = blockIdx.x;
  const int swz = (id & 7) * 64 + (id >> 3);  // XCD-aware: 512 blocks, 8 XCDs
  const int bx = swz >> 4, by = swz & 15;
  const int m0 = bx << 8, n0 = by << 8;
  const int tid = threadIdx.x, wv = tid >> 6, ln = tid & 63;
  const int wm = wv >> 2, wn = wv & 3;
  const int sr = tid >> 3;                   // staging row within instr group
  const int scs = (tid & 7) ^ (sr & 7);      // inverse-swizzled source chunk
  const bf16_t* Abase = A + ((size_t)(m0 + sr) << 10) + scs * 8;
  const bf16_t* Bbase = Bt + ((size_t)(n0 + sr) << 10) + scs * 8;

  f32x4 acc[8][4] = {};
  bf16x8 bfr[4][2];

#define STA(BUFI, H, J, KT) \
  gload16(Abase + (((H)*128 + (J)*64) << 10) + (KT)*64, &Al[BUFI][H][(J)*64 + wv * 8][0])
#define STB(BUFI, H, J, KT) \
  gload16(Bbase + (((H)*128 + (J)*64) << 10) + (KT)*64, &Bl[BUFI][H][(J)*64 + wv * 8][0])

#define PHASE(BUFI, MH, KK, LDB, STAGEC, WAITC) do {                           \
    bf16x8 af_[4];                                                             \
    _Pragma("unroll") for (int mi_ = 0; mi_ < 4; ++mi_) {                      \
      int ar_ = (MH)*64 + mi_*16 + (ln & 15);                                  \
      int ach_ = ((KK)*4 + (ln >> 4)) ^ (ar_ & 7);                             \
      af_[mi_] = *(const bf16x8*)&Al[BUFI][wm][ar_][ach_ * 8];                 \
    }                                                                          \
    if (LDB) {                                                                 \
      _Pragma("unroll") for (int ni_ = 0; ni_ < 4; ++ni_) {                    \
        int br_ = (wn & 1)*64 + ni_*16 + (ln & 15);                            \
        int bch_ = ((KK)*4 + (ln >> 4)) ^ (br_ & 7);                           \
        bfr[ni_][KK] = *(const bf16x8*)&Bl[BUFI][wn >> 1][br_][bch_ * 8];      \
      }                                                                        \
    }                                                                          \
    STAGEC;                                                                    \
    WAITC;                                                                     \
    __builtin_amdgcn_s_barrier();                                              \
    asm volatile("s_waitcnt lgkmcnt(0)" ::: "memory");                         \
    __builtin_amdgcn_s_setprio(1);                                             \
    _Pragma("unroll") for (int mi_ = 0; mi_ < 4; ++mi_)                        \
      _Pragma("unroll") for (int ni_ = 0; ni_ < 4; ++ni_)                      \
        acc[(MH)*4 + mi_][ni_] = __builtin_amdgcn_mfma_f32_16x16x32_bf16(      \
            af_[mi_], bfr[ni_][KK], acc[(MH)*4 + mi_][ni_], 0, 0, 0);          \
    __builtin_amdgcn_s_setprio(0);                                             \
    __builtin_amdgcn_s_barrier();                                              \
    asm volatile("" ::: "memory");                                             \
  } while (0)

  // ---- prologue: tile0 (A+B, 8 loads) + tile1.B (4 loads); wait tile0, keep tile1.B in flight
  STA(0, 0, 0, 0); STA(0, 0, 1, 0); STA(0, 1, 0, 0); STA(0, 1, 1, 0);
  STB(0, 0, 0, 0); STB(0, 0, 1, 0); STB(0, 1, 0, 0); STB(0, 1, 1, 0);
  STB(1, 0, 0, 1); STB(1, 0, 1, 1); STB(1, 1, 0, 1); STB(1, 1, 1, 1);
  asm volatile("s_waitcnt vmcnt(4)" ::: "memory");
  __builtin_amdgcn_s_barrier();
  asm volatile("" ::: "memory");

  // steady iteration i: consume buf0=tile 2i (p1-p4), buf1=tile 2i+1 (p5-p8).
  // stage: p1/p2 buf1.A(2i+1); p3/p4 buf0.B(2i+2); p5/p6 buf0.A(2i+2); p7/p8 buf1.B(2i+3).
  // checkpoints: vmcnt(4) at p4 (covers tile 2i+1) and p8 (covers tile 2i+2).
#pragma unroll 1
  for (int i = 0; i < 8; ++i) {
    const int to = 2 * i + 1;
    PHASE(0, 0, 0, 1, ({ STA(1, 0, 0, to); STA(1, 0, 1, to); }), ((void)0));
    PHASE(0, 0, 1, 1, ({ STA(1, 1, 0, to); STA(1, 1, 1, to); }), ((void)0));
    PHASE(0, 1, 0, 0, ({ if (i < 7) { STB(0, 0, 0, to + 1); STB(0, 0, 1, to + 1); } }),
          ((void)0));
    PHASE(0, 1, 1, 0, ({ if (i < 7) { STB(0, 1, 0, to + 1); STB(0, 1, 1, to + 1); } }),
          ({ if (i < 7) { asm volatile("s_waitcnt vmcnt(4)" ::: "memory"); }
             else       { asm volatile("s_waitcnt vmcnt(0)" ::: "memory"); } }));
    PHASE(1, 0, 0, 1, ({ if (i < 7) { STA(0, 0, 0, to + 1); STA(0, 0, 1, to + 1); } }),
          ((void)0));
    PHASE(1, 0, 1, 1, ({ if (i < 7) { STA(0, 1, 0, to + 1); STA(0, 1, 1, to + 1); } }),
          ((void)0));
    PHASE(1, 1, 0, 0, ({ if (i < 7) { STB(1, 0, 0, to + 2); STB(1, 0, 1, to + 2); } }),
          ((void)0));
    PHASE(1, 1, 1, 0, ({ if (i < 7) { STB(1, 1, 0, to + 2); STB(1, 1, 1, to + 2); } }),
          ({ if (i < 7) { asm volatile("s_waitcnt vmcnt(4)" ::: "memory"); } }));
  }
#undef PHASE
#undef STA
#undef STB

  // ---- epilogue: widx uniform per block (by>>2). Q/K: fused RoPE. V: transposed.
  const int widx = n0 >> 10;
  const int cb = (n0 & 1023) + wn * 64;  // region-local col base (head-aligned)
  bf16_t* W = Obase + (size_t)widx * MM * EE;
  if (widx <= 1) {
    // RoPE in-register: d = ni*16+(ln&15); pair element is acc[mi][ni^2] (same lane)
#pragma unroll
    for (int mi = 0; mi < 8; ++mi) {
#pragma unroll
      for (int r = 0; r < 4; ++r) {
        int row = m0 + wm * 128 + mi * 16 + ((ln >> 4) << 2) + r;
        int s = row & (SS - 1);
        float cv[4], sv[4];
#pragma unroll
        for (int ni = 0; ni < 4; ++ni) {
          int d = ni * 16 + (ln & 15);
          cv[ni] = cosp[s * DD + d];
          sv[ni] = sinp[s * DD + d];
        }
#pragma unroll
        for (int ni = 0; ni < 4; ++ni) {
          float v = acc[mi][ni][r], p = acc[mi][ni ^ 2][r];
          float o = v * cv[ni] + (ni < 2 ? -p : p) * sv[ni];
          W[(size_t)row * EE + cb + ni * 16 + (ln & 15)] = (bf16_t)o;
        }
      }
    }
  } else if (widx == 2) {
#pragma unroll
    for (int mi = 0; mi < 8; ++mi)
#pragma unroll
      for (int ni = 0; ni < 4; ++ni) {
        int row = m0 + wm * 128 + mi * 16 + ((ln >> 4) << 2);
        int ncol = cb + ni * 16 + (ln & 15);
        int h = ncol >> 6, d = ncol & 63;
        int b = row >> 12, s = row & (SS - 1);
        bf16_t* p = W + (((size_t)b * HH + h) * DD + d) * SS + s;
#pragma unroll
        for (int r = 0; r < 4; ++r) p[r] = (bf16_t)acc[mi][ni][r];
      }
  } else {
#pragma unroll
    for (int mi = 0; mi < 8; ++mi)
#pragma unroll
      for (int ni = 0; ni < 4; ++ni) {
        int row = m0 + wm * 128 + mi * 16 + ((ln >> 4) << 2);
        int ncol = cb + ni * 16 + (ln & 15);
        bf16_t* p = W + (size_t)row * EE + ncol;
#pragma unroll
        for (int r = 0; r < 4; ++r) p[(size_t)r * EE] = (bf16_t)acc[mi][ni][r];
      }
  }
}

// ---------------- final GEMM (m97-style 128x128, f32 out) ----------------
__global__ __launch_bounds__(256) void gemm_out(const bf16_t* __restrict__ A,
                                                const bf16_t* __restrict__ Bt,
                                                float* __restrict__ O) {
  __shared__ bf16_t Al[128 * 64];
  __shared__ bf16_t Bl[128 * 64];
  const int m0 = blockIdx.x * 128;
  const int n0 = blockIdx.y * 128;
  const int tid = threadIdx.x;
  const int wv = tid >> 6, ln = tid & 63;
  const int wm = wv >> 1, wn = wv & 1;
  f32x4 acc[4][4] = {};

  for (int k0 = 0; k0 < EE; k0 += 64) {
    __syncthreads();
#pragma unroll
    for (int i = 0; i < 4; ++i) {
      int slot = i * 256 + wv * 64 + ln;
      int r = slot >> 3, c = slot & 7;
      int cs = c ^ (r & 7);
      gload16(A + (size_t)(m0 + r) * EE + k0 + cs * 8, Al + (size_t)(i * 256 + wv * 64) * 8);
      gload16(Bt + (size_t)(n0 + r) * EE + k0 + cs * 8, Bl + (size_t)(i * 256 + wv * 64) * 8);
    }
    __syncthreads();
#pragma unroll
    for (int kk = 0; kk < 2; ++kk) {
      bf16x8 af[4], bfr[4];
#pragma unroll
      for (int mi = 0; mi < 4; ++mi) {
        int row = wm * 64 + mi * 16 + (ln & 15);
        int ch = (kk * 4 + (ln >> 4)) ^ (row & 7);
        af[mi] = *(const bf16x8*)(Al + row * 64 + ch * 8);
      }
#pragma unroll
      for (int ni = 0; ni < 4; ++ni) {
        int row = wn * 64 + ni * 16 + (ln & 15);
        int ch = (kk * 4 + (ln >> 4)) ^ (row & 7);
        bfr[ni] = *(const bf16x8*)(Bl + row * 64 + ch * 8);
      }
#pragma unroll
      for (int mi = 0; mi < 4; ++mi)
#pragma unroll
        for (int ni = 0; ni < 4; ++ni)
          acc[mi][ni] = __builtin_amdgcn_mfma_f32_16x16x32_bf16(af[mi], bfr[ni], acc[mi][ni], 0, 0, 0);
    }
  }

#pragma unroll
  for (int mi = 0; mi < 4; ++mi)
#pragma unroll
    for (int ni = 0; ni < 4; ++ni) {
      int row = m0 + wm * 64 + mi * 16 + ((ln >> 4) << 2);
      int col = n0 + wn * 64 + ni * 16 + (ln & 15);
#pragma unroll
      for (int r = 0; r < 4; ++r) O[(size_t)(row + r) * EE + col] = acc[mi][ni][r];
    }
}

// ---------------- block-diagonal attention + fused sigmoid gate ----------------
// grid: B*nb*H blocks; 4 waves; K/V double-buffered, prefetch kc+1 before compute kc.
__global__ __launch_bounds__(256) void attn_kernel(const bf16_t* __restrict__ Q,
                                                   const bf16_t* __restrict__ Kc,
                                                   const bf16_t* __restrict__ Vt,
                                                   const bf16_t* __restrict__ G,
                                                   bf16_t* __restrict__ AO) {
  __shared__ bf16_t Kl[2][64 * 64];
  __shared__ bf16_t Vl[2][64 * 64];
  __shared__ bf16_t Pl[4][64 * 64];
  const int bx = blockIdx.x;
  const int h = bx & 15, sb = (bx >> 4) & 15, b = bx >> 8;
  const int tid = threadIdx.x, wv = tid >> 6, ln = tid & 63;
  const int qrow0 = b * SS + sb * 256 + wv * 64;

  bf16x8 qf[4][2];
#pragma unroll
  for (int mi = 0; mi < 4; ++mi)
#pragma unroll
    for (int kk = 0; kk < 2; ++kk)
      qf[mi][kk] = *(const bf16x8*)(Q + (size_t)(qrow0 + mi * 16 + (ln & 15)) * EE +
                                    h * DD + kk * 32 + ((ln >> 4) << 3));

  f32x4 o[4][4] = {};
  float mr[4][4], lr[4][4];
#pragma unroll
  for (int i = 0; i < 4; ++i)
#pragma unroll
    for (int r = 0; r < 4; ++r) { mr[i][r] = -1e30f; lr[i][r] = 0.f; }

#define STAGE_KV(KC, BI) do {                                                        \
    const int krow0_ = b * SS + sb * 256 + (KC) * 64;                                \
    _Pragma("unroll") for (int i_ = 0; i_ < 2; ++i_) {                               \
      int slot_ = i_ * 256 + wv * 64 + ln;                                           \
      int r_ = slot_ >> 3, c_ = slot_ & 7, cs_ = c_ ^ (r_ & 7);                      \
      gload16(Kc + (size_t)(krow0_ + r_) * EE + h * DD + cs_ * 8,                    \
              &Kl[BI][(i_ * 256 + wv * 64) * 8]);                                    \
      gload16(Vt + (((size_t)b * HH + h) * DD + r_) * SS + sb * 256 + (KC) * 64 +    \
                  cs_ * 8,                                                           \
              &Vl[BI][(i_ * 256 + wv * 64) * 8]);                                    \
    }                                                                                \
  } while (0)

  STAGE_KV(0, 0);
  __syncthreads();

  for (int kc = 0; kc < 4; ++kc) {
    const int cur = kc & 1;
    if (kc < 3) STAGE_KV(kc + 1, cur ^ 1);  // prefetch; drained by end-of-iter sync

    f32x4 sc[4][4] = {};
    __builtin_amdgcn_s_setprio(1);
#pragma unroll
    for (int kk = 0; kk < 2; ++kk) {
      bf16x8 kf[4];
#pragma unroll
      for (int ni = 0; ni < 4; ++ni) {
        int row = ni * 16 + (ln & 15);
        int ch = (kk * 4 + (ln >> 4)) ^ (row & 7);
        kf[ni] = *(const bf16x8*)(&Kl[cur][row * 64 + ch * 8]);
      }
#pragma unroll
      for (int mi = 0; mi < 4; ++mi)
#pragma unroll
        for (int ni = 0; ni < 4; ++ni)
          sc[mi][ni] = __builtin_amdgcn_mfma_f32_16x16x32_bf16(qf[mi][kk], kf[ni], sc[mi][ni], 0, 0, 0);
    }
    __builtin_amdgcn_s_setprio(0);
#pragma unroll
    for (int mi = 0; mi < 4; ++mi)
#pragma unroll
      for (int ni = 0; ni < 4; ++ni) sc[mi][ni] *= 0.125f;

#pragma unroll
    for (int mi = 0; mi < 4; ++mi) {
#pragma unroll
      for (int r = 0; r < 4; ++r) {
        float mx = fmaxf(fmaxf(sc[mi][0][r], sc[mi][1][r]), fmaxf(sc[mi][2][r], sc[mi][3][r]));
#pragma unroll
        for (int d = 1; d < 16; d <<= 1) mx = fmaxf(mx, __shfl_xor(mx, d));
        float mn = fmaxf(mr[mi][r], mx);
        float scal = __expf(mr[mi][r] - mn);
        mr[mi][r] = mn;
        float rs = 0.f;
#pragma unroll
        for (int ni = 0; ni < 4; ++ni) {
          float p = __expf(sc[mi][ni][r] - mn);
          sc[mi][ni][r] = p;
          rs += p;
        }
#pragma unroll
        for (int d = 1; d < 16; d <<= 1) rs += __shfl_xor(rs, d);
        lr[mi][r] = lr[mi][r] * scal + rs;
#pragma unroll
        for (int nd = 0; nd < 4; ++nd) o[mi][nd][r] *= scal;
      }
    }

    bf16_t* P = Pl[wv];
#pragma unroll
    for (int mi = 0; mi < 4; ++mi)
#pragma unroll
      for (int ni = 0; ni < 4; ++ni)
#pragma unroll
        for (int r = 0; r < 4; ++r) {
          int row = mi * 16 + ((ln >> 4) << 2) + r;
          int col = ni * 16 + (ln & 15);
          P[row * 64 + (col ^ ((row & 7) << 3))] = (bf16_t)sc[mi][ni][r];
        }
    __builtin_amdgcn_s_setprio(1);
#pragma unroll
    for (int kk = 0; kk < 2; ++kk) {
      bf16x8 pf[4], vf[4];
#pragma unroll
      for (int mi = 0; mi < 4; ++mi) {
        int row = mi * 16 + (ln & 15);
        int ch = (kk * 4 + (ln >> 4)) ^ (row & 7);
        pf[mi] = *(const bf16x8*)(P + row * 64 + ch * 8);
      }
#pragma unroll
      for (int nd = 0; nd < 4; ++nd) {
        int row = nd * 16 + (ln & 15);
        int ch = (kk * 4 + (ln >> 4)) ^ (row & 7);
        vf[nd] = *(const bf16x8*)(&Vl[cur][row * 64 + ch * 8]);
      }
#pragma unroll
      for (int mi = 0; mi < 4; ++mi)
#pragma unroll
        for (int nd = 0; nd < 4; ++nd)
          o[mi][nd] = __builtin_amdgcn_mfma_f32_16x16x32_bf16(pf[mi], vf[nd], o[mi][nd], 0, 0, 0);
    }
    __builtin_amdgcn_s_setprio(0);
    __syncthreads();  // drains prefetch vmcnt + LDS reuse fence
  }
#undef STAGE_KV

#pragma unroll
  for (int mi = 0; mi < 4; ++mi)
#pragma unroll
    for (int nd = 0; nd < 4; ++nd)
#pragma unroll
      for (int r = 0; r < 4; ++r) {
        int m = qrow0 + mi * 16 + ((ln >> 4) << 2) + r;
        int col = h * DD + nd * 16 + (ln & 15);
        float gv = (float)G[(size_t)m * EE + col];
        float sig = 1.f / (1.f + __expf(-gv));
        AO[(size_t)m * EE + col] = (bf16_t)((o[mi][nd][r] / lr[mi][r]) * sig);
      }
}

extern "C" void kernel_launch(void* const* d_in, const int* in_sizes, int n_in,
                              void* d_out, int out_size, void* d_ws, size_t ws_size,
                              hipStream_t stream) {
  const float* x = (const float*)d_in[0];
  const float* Wq = (const float*)d_in[1];
  const float* Wk = (const float*)d_in[2];
  const float* Wv = (const float*)d_in[3];
  const float* Wg = (const float*)d_in[4];
  const float* Wo = (const float*)d_in[5];
  const float* cosp = (const float*)d_in[6];
  const float* sinp = (const float*)d_in[7];
  float* out = (float*)d_out;

  char* ws = (char*)d_ws;
  bf16_t* XB = (bf16_t*)(ws);                       // 16MB: x bf16; reused as gated AO
  bf16_t* WT = (bf16_t*)(ws + (16ll << 20));        // 10MB: [5][1024][1024] W^T bf16 (q,k,v,g,o)
  bf16_t* QB = (bf16_t*)(ws + (26ll << 20));        // 16MB: Q (roped)
  bf16_t* KB = (bf16_t*)(ws + (42ll << 20));        // 16MB: K (roped)
  bf16_t* VT = (bf16_t*)(ws + (58ll << 20));        // 16MB: V transposed [B][H][D][S]
  bf16_t* GB = (bf16_t*)(ws + (74ll << 20));        // 16MB: gate
  bf16_t* AO = XB;                                  // gated attention output reuses XB region

  const int n8 = MM * EE / 8;  // 1048576
  cvt_kernel<<<n8 / 256, 256, 0, stream>>>(x, XB, n8);
  wt_kernel<<<dim3(32, 32, 5), 256, 0, stream>>>(Wq, Wk, Wv, Wg, Wo, WT);
  gemm8p<<<512, 512, 0, stream>>>(XB, WT, QB, cosp, sinp);
  attn_kernel<<<BB * (SS / 256) * HH, 256, 0, stream>>>(QB, KB, VT, GB, AO);
  gemm_out<<<dim3(MM / 128, EE / 128), 256, 0, stream>>>(AO, WT + (size_t)4 * EE * EE, out);
}